// Round 1
// baseline (273.102 us; speedup 1.0000x reference)
//
#include <hip/hip_runtime.h>

#define B_ 8
#define L_ 16
#define H_ 16
#define D_ 64
#define DM 1024
#define S_ 8192

// ---------------- P1/P5: split-K GEMM, M=128, BN=64, BK=32 ----------------
__global__ void __launch_bounds__(256) gemm_splitk_kernel(
    const float* __restrict__ A, const float* __restrict__ W,
    float* __restrict__ part, int lda, int ldw, int Kchunk)
{
  const int c0 = blockIdx.x * 64;
  const int k0 = blockIdx.y * Kchunk;
  const int t  = threadIdx.x;
  __shared__ float xs[32][132];   // A tile transposed, padded (132%4==0 keeps b128 align)
  __shared__ float wsm[32][64];   // W tile
  float acc[8][4];
  #pragma unroll
  for (int i = 0; i < 8; ++i)
    #pragma unroll
    for (int j = 0; j < 4; ++j) acc[i][j] = 0.f;
  const int rg = t >> 4, cg = t & 15;
  const int r0 = rg * 8, ct0 = cg * 4;
  for (int ks = 0; ks < Kchunk; ks += 32) {
    __syncthreads();
    #pragma unroll
    for (int i = 0; i < 4; ++i) {           // stage A: 128 rows x 32 k, transposed
      int fi = t + i * 256;
      int r = fi >> 3, kq = fi & 7;
      float4 v = *(const float4*)(A + (size_t)r * lda + k0 + ks + kq * 4);
      xs[kq*4+0][r] = v.x; xs[kq*4+1][r] = v.y;
      xs[kq*4+2][r] = v.z; xs[kq*4+3][r] = v.w;
    }
    #pragma unroll
    for (int i = 0; i < 2; ++i) {           // stage W: 32 k x 64 c
      int si = t + i * 256;
      int kk = si >> 4, cq = si & 15;
      *(float4*)&wsm[kk][cq*4] =
          *(const float4*)(W + (size_t)(k0 + ks + kk) * ldw + c0 + cq * 4);
    }
    __syncthreads();
    #pragma unroll
    for (int kk = 0; kk < 32; ++kk) {
      float a[8], bb[4];
      *(float4*)&a[0] = *(const float4*)&xs[kk][r0];
      *(float4*)&a[4] = *(const float4*)&xs[kk][r0 + 4];
      *(float4*)&bb[0] = *(const float4*)&wsm[kk][ct0];
      #pragma unroll
      for (int ii = 0; ii < 8; ++ii)
        #pragma unroll
        for (int jj = 0; jj < 4; ++jj)
          acc[ii][jj] = fmaf(a[ii], bb[jj], acc[ii][jj]);
    }
  }
  float* po = part + (size_t)blockIdx.y * 128 * ldw;
  #pragma unroll
  for (int ii = 0; ii < 8; ++ii)
    #pragma unroll
    for (int jj = 0; jj < 4; ++jj)
      po[(size_t)(r0 + ii) * ldw + c0 + ct0 + jj] = acc[ii][jj];
}

// ---------------- P2: reduce split-K partials + bias + RoPE ----------------
// one thread per (b,h,l,pair i); q is pre-scaled by 1/sqrt(D)=0.125
__global__ void ropefuse_kernel(const float* __restrict__ part,
                                const float* __restrict__ bias,
                                const int* __restrict__ cidx,
                                float* __restrict__ qh, float* __restrict__ kn,
                                float* __restrict__ vn)
{
  int gt = blockIdx.x * 256 + threadIdx.x;     // 65536 = 8*16*16*32
  int i = gt & 31, l = (gt >> 5) & 15, h = (gt >> 9) & 15, b = gt >> 13;
  int row = b * L_ + l;
  const int PS = 128 * 3072;
  const float* pr = part + (size_t)row * 3072;
  int cq = h * 64 + i;
  int cols[6] = {cq, cq + 32, 1024 + cq, 1024 + cq + 32, 2048 + cq, 2048 + cq + 32};
  float v[6];
  #pragma unroll
  for (int c = 0; c < 6; ++c) {
    float s = bias[cols[c]];
    #pragma unroll
    for (int ks = 0; ks < 4; ++ks) s += pr[(size_t)ks * PS + cols[c]];
    v[c] = s;
  }
  int pos = cidx[0] + l;
  // inv_freq = 10000^(-i/32) = exp2(-i/32 * log2(10000))
  float inv = exp2f((float)i * (-13.287712379549449f / 32.0f));
  float fr = (float)pos * inv;
  float sn, cs;
  sincosf(fr, &sn, &cs);
  int ob = ((b * H_ + h) * L_ + l) * 64;       // [B][H][L][D]
  qh[ob + i]      = (v[0] * cs - v[1] * sn) * 0.125f;
  qh[ob + 32 + i] = (v[1] * cs + v[0] * sn) * 0.125f;
  kn[ob + i]      = v[2] * cs - v[3] * sn;
  kn[ob + 32 + i] = v[3] * cs + v[2] * sn;
  vn[ob + i]      = v[4];
  vn[ob + 32 + i] = v[5];
}

// ---------------- P3: partial flash attention over the 8192 cache ----------
// grid (8 chunks, 128 bh); block 256 = 4 waves; wave owns 4 l's.
// K tile XOR-swizzled (16B slot ^= row&7) so phase-A per-row b128 reads hit
// the 1KB/8cyc LDS floor; V tile linear (phase-B reads are lane-consecutive).
__global__ void __launch_bounds__(256, 4) attn_partial_kernel(
    const float* __restrict__ qh, const float* __restrict__ kc,
    const float* __restrict__ vc, float* __restrict__ opart,
    float* __restrict__ mpart, float* __restrict__ lpart)
{
  const int chunk = blockIdx.x;
  const int bh = blockIdx.y;
  const int b = bh >> 4, h = bh & 15;
  const int tid = threadIdx.x;
  const int w = tid >> 6, lane = tid & 63;
  __shared__ float kt[64 * 64];   // 16 KB
  __shared__ float vt[64 * 64];   // 16 KB
  __shared__ float ql[16 * 64];   // 4 KB (q pre-scaled)
  __shared__ float pl[16 * 64];   // 4 KB (per-wave private rows)
  {
    int l = tid >> 4, sl = tid & 15;
    *(float4*)&ql[l * 64 + sl * 4] = *(const float4*)&qh[(size_t)(bh * 16 + l) * 64 + sl * 4];
  }
  const int Lg = w * 4;
  float m_run[4], l_run[4], o[4];
  #pragma unroll
  for (int li = 0; li < 4; ++li) { m_run[li] = -1e30f; l_run[li] = 0.f; o[li] = 0.f; }
  const size_t base = (size_t)b * S_ * DM + (size_t)h * 64;
  const int s_base = chunk * 1024;
  for (int tt = 0; tt < 16; ++tt) {
    const int s_tile = s_base + tt * 64;
    __syncthreads();
    #pragma unroll
    for (int i = 0; i < 4; ++i) {           // stage K (swizzled) + V (linear)
      int fi = tid + i * 256;
      int r = fi >> 4, p = fi & 15;
      int j = p ^ (r & 7);
      *(float4*)&kt[r * 64 + p * 4] =
          *(const float4*)&kc[base + (size_t)(s_tile + r) * DM + j * 4];
      *(float4*)&vt[r * 64 + p * 4] =
          *(const float4*)&vc[base + (size_t)(s_tile + r) * DM + p * 4];
    }
    __syncthreads();
    // ---- phase A: scores, lane <-> s-row ----
    float sc[4] = {0.f, 0.f, 0.f, 0.f};
    #pragma unroll
    for (int dc = 0; dc < 16; ++dc) {
      int pp = dc ^ (lane & 7);
      float4 kv = *(const float4*)&kt[lane * 64 + pp * 4];
      #pragma unroll
      for (int li = 0; li < 4; ++li) {
        float4 qv = *(const float4*)&ql[(Lg + li) * 64 + dc * 4];
        sc[li] += kv.x * qv.x + kv.y * qv.y + kv.z * qv.z + kv.w * qv.w;
      }
    }
    // ---- online softmax (wave-wide butterfly) ----
    #pragma unroll
    for (int li = 0; li < 4; ++li) {
      float mx = sc[li];
      #pragma unroll
      for (int d = 1; d < 64; d <<= 1) mx = fmaxf(mx, __shfl_xor(mx, d));
      float m_new = fmaxf(m_run[li], mx);
      float c = __expf(m_run[li] - m_new);
      float p = __expf(sc[li] - m_new);
      float sm = p;
      #pragma unroll
      for (int d = 1; d < 64; d <<= 1) sm += __shfl_xor(sm, d);
      l_run[li] = l_run[li] * c + sm;
      m_run[li] = m_new;
      o[li] *= c;
      pl[(Lg + li) * 64 + lane] = p;  // same-wave transpose buffer, no barrier needed
    }
    // ---- phase B: O += P*V, lane <-> d ----
    float pv[4][4];
    #pragma unroll
    for (int s4 = 0; s4 < 16; ++s4) {
      #pragma unroll
      for (int li = 0; li < 4; ++li)
        *(float4*)&pv[li][0] = *(const float4*)&pl[(Lg + li) * 64 + s4 * 4];
      #pragma unroll
      for (int j = 0; j < 4; ++j) {
        float vv = vt[(s4 * 4 + j) * 64 + lane];
        #pragma unroll
        for (int li = 0; li < 4; ++li) o[li] = fmaf(pv[li][j], vv, o[li]);
      }
    }
  }
  #pragma unroll
  for (int li = 0; li < 4; ++li)
    opart[(((size_t)chunk * 128 + bh) * 16 + Lg + li) * 64 + lane] = o[li];
  if (lane == 0) {
    #pragma unroll
    for (int li = 0; li < 4; ++li) {
      mpart[(chunk * 128 + bh) * 16 + Lg + li] = m_run[li];
      lpart[(chunk * 128 + bh) * 16 + Lg + li] = l_run[li];
    }
  }
}

// ---------------- P4: merge 8 chunk partials + 16 new tokens ---------------
__global__ void __launch_bounds__(64) combine_kernel(
    const float* __restrict__ qh, const float* __restrict__ kn,
    const float* __restrict__ vn, const float* __restrict__ opart,
    const float* __restrict__ mpart, const float* __restrict__ lpart,
    float* __restrict__ attn)
{
  const int bh = blockIdx.x;
  const int b = bh >> 4, h = bh & 15;
  const int lane = threadIdx.x;
  __shared__ float qb[1024], kb[1024], vb[1024];
  __shared__ float scn[16][16];
  for (int l = 0; l < 16; ++l) {
    qb[l * 64 + lane] = qh[(size_t)(bh * 16 + l) * 64 + lane];
    kb[l * 64 + lane] = kn[(size_t)(bh * 16 + l) * 64 + lane];
    vb[l * 64 + lane] = vn[(size_t)(bh * 16 + l) * 64 + lane];
  }
  __syncthreads();
  {
    int l = lane >> 2, sp0 = (lane & 3) * 4;
    for (int jj = 0; jj < 4; ++jj) {
      int sp = sp0 + jj;
      float a = 0.f;
      for (int d = 0; d < 64; ++d) a += qb[l * 64 + d] * kb[sp * 64 + d];
      scn[l][sp] = a;   // q already carries the 1/8 scale
    }
  }
  __syncthreads();
  for (int l = 0; l < 16; ++l) {
    float mc[8], lc[8];
    float m_tot = -1e30f;
    #pragma unroll
    for (int c = 0; c < 8; ++c) {
      mc[c] = mpart[(c * 128 + bh) * 16 + l];
      lc[c] = lpart[(c * 128 + bh) * 16 + l];
      m_tot = fmaxf(m_tot, mc[c]);
    }
    for (int sp = 0; sp < 16; ++sp) m_tot = fmaxf(m_tot, scn[l][sp]);
    float den = 0.f, od = 0.f;
    #pragma unroll
    for (int c = 0; c < 8; ++c) {
      float e = __expf(mc[c] - m_tot);
      den += lc[c] * e;
      od += opart[(((size_t)c * 128 + bh) * 16 + l) * 64 + lane] * e;
    }
    for (int sp = 0; sp < 16; ++sp) {
      float p = __expf(scn[l][sp] - m_tot);
      den += p;
      od += p * vb[sp * 64 + lane];
    }
    attn[((size_t)(b * 16 + l) * 16 + h) * 64 + lane] = od / den;
  }
}

// ---------------- P6: reduce O-proj split-K partials + bias ---------------
__global__ void reduce_out_kernel(const float* __restrict__ part2,
                                  const float* __restrict__ ob,
                                  float* __restrict__ out)
{
  int idx = blockIdx.x * 256 + threadIdx.x;  // 131072
  int c = idx & 1023;
  float s = ob[c];
  #pragma unroll
  for (int ks = 0; ks < 8; ++ks) s += part2[(size_t)ks * 131072 + idx];
  out[idx] = s;
}

extern "C" void kernel_launch(void* const* d_in, const int* in_sizes, int n_in,
                              void* d_out, int out_size, void* d_ws, size_t ws_size,
                              hipStream_t stream) {
  (void)in_sizes; (void)n_in; (void)out_size; (void)ws_size;
  const float* x       = (const float*)d_in[0];
  const float* cache_k = (const float*)d_in[1];
  const float* cache_v = (const float*)d_in[2];
  const float* qkv_w   = (const float*)d_in[3];
  const float* qkv_b   = (const float*)d_in[4];
  const float* o_w     = (const float*)d_in[5];
  const float* o_b     = (const float*)d_in[6];
  const int*   cidx    = (const int*)d_in[7];
  float* out = (float*)d_out;

  float* ws    = (float*)d_ws;
  float* part1 = ws;                     // 4*128*3072 = 1572864
  float* qh    = part1 + 1572864;        // 131072  [B][H][L][D], pre-scaled
  float* kn    = qh + 131072;            // 131072
  float* vn    = kn + 131072;            // 131072
  float* opart = vn + 131072;            // 8*128*16*64 = 1048576
  float* mpart = opart + 1048576;        // 16384
  float* lpart = mpart + 16384;          // 16384
  float* attn  = lpart + 16384;          // 131072
  float* part2 = attn + 131072;          // 8*128*1024 = 1048576
  // total ~16.9 MB of d_ws

  // P1: qkv = x @ qkv_w (split-K 4)
  gemm_splitk_kernel<<<dim3(48, 4), 256, 0, stream>>>(x, qkv_w, part1, 1024, 3072, 256);
  // P2: reduce + bias + RoPE -> qh (scaled), kn, vn
  ropefuse_kernel<<<256, 256, 0, stream>>>(part1, qkv_b, cidx, qh, kn, vn);
  // P3: partial attention over the 8192-deep cache
  attn_partial_kernel<<<dim3(8, 128), 256, 0, stream>>>(qh, cache_k, cache_v,
                                                        opart, mpart, lpart);
  // P4: merge partials + 16 new tokens -> attn (128 x 1024)
  combine_kernel<<<128, 64, 0, stream>>>(qh, kn, vn, opart, mpart, lpart, attn);
  // P5: attn @ o_w (split-K 8)
  gemm_splitk_kernel<<<dim3(16, 8), 256, 0, stream>>>(attn, o_w, part2, 1024, 1024, 128);
  // P6: reduce + bias -> out
  reduce_out_kernel<<<512, 256, 0, stream>>>(part2, o_b, out);
}